// Round 6
// baseline (64.400 us; speedup 1.0000x reference)
//
#include <hip/hip_runtime.h>
#include <hip/hip_bf16.h>

// Single-dispatch segment-mean gather.
// One WAVE per segment; wave-uniform binary search on sorted segment_ids for
// the segment start (no scan dispatch, no workspace). Row = 128 floats = 512B.
// Half-wave float4 gather: lanes 0-31 read row r(2i), lanes 32-63 read row
// r(2i+1) -> each load moves 1024B (2 rows). Single predicated full-width
// body: 8 loads (16 rows) in flight per iteration, no serialized tail.
// Out-of-range edges load row 0 (idx_l=0 fallback; L2-resident, ~free) and
// their accumulate is predicated off. All __shfl in uniform control flow.
#define WPB 4   // waves (=segments) per block

__global__ __launch_bounds__(64 * WPB) void seg_mean_wave_kernel(
    const float* __restrict__ input,
    const int*   __restrict__ idxn,
    const int*   __restrict__ seg_ids,   // sorted ascending, len E
    const int*   __restrict__ degs,
    float*       __restrict__ out,
    int E, int S) {
    int tid  = threadIdx.x;
    int lane = tid & 63;
    int s    = blockIdx.x * WPB + (tid >> 6);
    if (s >= S) return;

    int deg = degs[s];

    // first edge index with seg_ids[e] >= s (wave-uniform)
    int lo = 0, hi = E;
    while (lo < hi) {
        int mid = (lo + hi) >> 1;
        if (seg_ids[mid] < s) lo = mid + 1; else hi = mid;
    }
    int start = lo;

    int half = lane >> 5;   // which row of each pair this half-wave reads
    int c4   = lane & 31;   // float4 slot within the 128-float row

    const float4* __restrict__ in4 = (const float4*)input;
    float4 z = make_float4(0.f, 0.f, 0.f, 0.f);
    float4 a0 = z, a1 = z, a2 = z, a3 = z, a4 = z, a5 = z, a6 = z, a7 = z;

    for (int base = 0; base < deg; base += 64) {
        int cnt = deg - base; if (cnt > 64) cnt = 64;
        // one coalesced load of up to 64 indices into lane registers;
        // lanes >= cnt hold 0 (valid register -> safe shfl source, row 0)
        int idx_l = (lane < cnt) ? idxn[start + base + lane] : 0;

        // 16 rows per iteration, 8 independent 1KB loads in flight.
        // shfl source lane e+k+half <= 63 always (e multiple of 16, <=48).
        for (int e = 0; e < cnt; e += 16) {
            int r0 = __shfl(idx_l, e +  0 + half);
            int r1 = __shfl(idx_l, e +  2 + half);
            int r2 = __shfl(idx_l, e +  4 + half);
            int r3 = __shfl(idx_l, e +  6 + half);
            int r4 = __shfl(idx_l, e +  8 + half);
            int r5 = __shfl(idx_l, e + 10 + half);
            int r6 = __shfl(idx_l, e + 12 + half);
            int r7 = __shfl(idx_l, e + 14 + half);
            float4 v0 = in4[(size_t)r0 * 32 + c4];
            float4 v1 = in4[(size_t)r1 * 32 + c4];
            float4 v2 = in4[(size_t)r2 * 32 + c4];
            float4 v3 = in4[(size_t)r3 * 32 + c4];
            float4 v4 = in4[(size_t)r4 * 32 + c4];
            float4 v5 = in4[(size_t)r5 * 32 + c4];
            float4 v6 = in4[(size_t)r6 * 32 + c4];
            float4 v7 = in4[(size_t)r7 * 32 + c4];
            if (e +  0 + half < cnt) { a0.x += v0.x; a0.y += v0.y; a0.z += v0.z; a0.w += v0.w; }
            if (e +  2 + half < cnt) { a1.x += v1.x; a1.y += v1.y; a1.z += v1.z; a1.w += v1.w; }
            if (e +  4 + half < cnt) { a2.x += v2.x; a2.y += v2.y; a2.z += v2.z; a2.w += v2.w; }
            if (e +  6 + half < cnt) { a3.x += v3.x; a3.y += v3.y; a3.z += v3.z; a3.w += v3.w; }
            if (e +  8 + half < cnt) { a4.x += v4.x; a4.y += v4.y; a4.z += v4.z; a4.w += v4.w; }
            if (e + 10 + half < cnt) { a5.x += v5.x; a5.y += v5.y; a5.z += v5.z; a5.w += v5.w; }
            if (e + 12 + half < cnt) { a6.x += v6.x; a6.y += v6.y; a6.z += v6.z; a6.w += v6.w; }
            if (e + 14 + half < cnt) { a7.x += v7.x; a7.y += v7.y; a7.z += v7.z; a7.w += v7.w; }
        }
    }

    a0.x += a1.x; a0.y += a1.y; a0.z += a1.z; a0.w += a1.w;
    a2.x += a3.x; a2.y += a3.y; a2.z += a3.z; a2.w += a3.w;
    a4.x += a5.x; a4.y += a5.y; a4.z += a5.z; a4.w += a5.w;
    a6.x += a7.x; a6.y += a7.y; a6.z += a7.z; a6.w += a7.w;
    a0.x += a2.x; a0.y += a2.y; a0.z += a2.z; a0.w += a2.w;
    a4.x += a6.x; a4.y += a6.y; a4.z += a6.z; a4.w += a6.w;
    a0.x += a4.x; a0.y += a4.y; a0.z += a4.z; a0.w += a4.w;

    // combine the two half-wave partials (lane l <-> lane l^32)
    a0.x += __shfl_xor(a0.x, 32);
    a0.y += __shfl_xor(a0.y, 32);
    a0.z += __shfl_xor(a0.z, 32);
    a0.w += __shfl_xor(a0.w, 32);

    if (half == 0) {
        float inv = (deg > 0) ? (1.f / (float)deg) : 0.f;
        float4 res = make_float4(a0.x * inv, a0.y * inv, a0.z * inv, a0.w * inv);
        ((float4*)out)[(size_t)s * 32 + c4] = res;
    }
}

extern "C" void kernel_launch(void* const* d_in, const int* in_sizes, int n_in,
                              void* d_out, int out_size, void* d_ws, size_t ws_size,
                              hipStream_t stream) {
    const float* input   = (const float*)d_in[0];
    const int*   idxn    = (const int*)d_in[1];
    const int*   seg_ids = (const int*)d_in[2];
    const int*   degs    = (const int*)d_in[3];

    int E = in_sizes[1];
    int S = in_sizes[3];
    float* out = (float*)d_out;

    int nblk = (S + WPB - 1) / WPB;
    seg_mean_wave_kernel<<<nblk, 64 * WPB, 0, stream>>>(
        input, idxn, seg_ids, degs, out, E, S);
}

// Round 7
// 61.140 us; speedup vs baseline: 1.0533x; 1.0533x over previous
//
#include <hip/hip_runtime.h>
#include <hip/hip_bf16.h>

// Single-dispatch segment-mean gather.
// One WAVE per segment; wave-uniform binary search on sorted segment_ids for
// the segment start. Row = 128 floats = 512B. Half-wave float4 gather:
// lanes 0-31 read row r(2i), lanes 32-63 read row r(2i+1) -> each load
// moves 1024B (2 rows); 4 loads (8 rows) in flight per body iteration with
// ZERO dead slots. One predicated tail iteration (clamped shuffle source ->
// dup of last real row, L1-hit) replaces the serialized scalar tail.
// All __shfl calls in uniform control flow with valid active source lanes.
#define WPB 4   // waves (=segments) per block

__global__ __launch_bounds__(64 * WPB) void seg_mean_wave_kernel(
    const float* __restrict__ input,
    const int*   __restrict__ idxn,
    const int*   __restrict__ seg_ids,   // sorted ascending, len E
    const int*   __restrict__ degs,
    float*       __restrict__ out,
    int E, int S) {
    int tid  = threadIdx.x;
    int lane = tid & 63;
    int s    = blockIdx.x * WPB + (tid >> 6);
    if (s >= S) return;

    int deg = degs[s];

    // first edge index with seg_ids[e] >= s (wave-uniform)
    int lo = 0, hi = E;
    while (lo < hi) {
        int mid = (lo + hi) >> 1;
        if (seg_ids[mid] < s) lo = mid + 1; else hi = mid;
    }
    int start = lo;

    int half = lane >> 5;   // which row of each pair this half-wave reads
    int c4   = lane & 31;   // float4 slot within the 128-float row

    const float4* __restrict__ in4 = (const float4*)input;
    float4 z = make_float4(0.f, 0.f, 0.f, 0.f);
    float4 a0 = z, a1 = z, a2 = z, a3 = z;

    for (int base = 0; base < deg; base += 64) {
        int cnt = deg - base; if (cnt > 64) cnt = 64;
        // one coalesced load of up to 64 indices into lane registers
        int idx_l = (lane < cnt) ? idxn[start + base + lane] : 0;

        int e = 0;
        // body: 8 rows per iteration, 4 independent 1KB loads, no waste
        for (; e + 8 <= cnt; e += 8) {
            int r0 = __shfl(idx_l, e + 0 + half);
            int r1 = __shfl(idx_l, e + 2 + half);
            int r2 = __shfl(idx_l, e + 4 + half);
            int r3 = __shfl(idx_l, e + 6 + half);
            float4 v0 = in4[(size_t)r0 * 32 + c4];
            float4 v1 = in4[(size_t)r1 * 32 + c4];
            float4 v2 = in4[(size_t)r2 * 32 + c4];
            float4 v3 = in4[(size_t)r3 * 32 + c4];
            a0.x += v0.x; a0.y += v0.y; a0.z += v0.z; a0.w += v0.w;
            a1.x += v1.x; a1.y += v1.y; a1.z += v1.z; a1.w += v1.w;
            a2.x += v2.x; a2.y += v2.y; a2.z += v2.z; a2.w += v2.w;
            a3.x += v3.x; a3.y += v3.y; a3.z += v3.z; a3.w += v3.w;
        }
        // single predicated tail iteration: 4 concurrent loads; dead slots
        // clamp to the last real edge (same 512B line -> L1 hit) and their
        // accumulate is predicated off. Source lanes always valid & active.
        if (e < cnt) {
            int last = cnt - 1;
            int l0 = e + 0 + half; l0 = l0 < last ? l0 : last;
            int l1 = e + 2 + half; l1 = l1 < last ? l1 : last;
            int l2 = e + 4 + half; l2 = l2 < last ? l2 : last;
            int l3 = e + 6 + half; l3 = l3 < last ? l3 : last;
            int r0 = __shfl(idx_l, l0);
            int r1 = __shfl(idx_l, l1);
            int r2 = __shfl(idx_l, l2);
            int r3 = __shfl(idx_l, l3);
            float4 v0 = in4[(size_t)r0 * 32 + c4];
            float4 v1 = in4[(size_t)r1 * 32 + c4];
            float4 v2 = in4[(size_t)r2 * 32 + c4];
            float4 v3 = in4[(size_t)r3 * 32 + c4];
            if (e + 0 + half < cnt) { a0.x += v0.x; a0.y += v0.y; a0.z += v0.z; a0.w += v0.w; }
            if (e + 2 + half < cnt) { a1.x += v1.x; a1.y += v1.y; a1.z += v1.z; a1.w += v1.w; }
            if (e + 4 + half < cnt) { a2.x += v2.x; a2.y += v2.y; a2.z += v2.z; a2.w += v2.w; }
            if (e + 6 + half < cnt) { a3.x += v3.x; a3.y += v3.y; a3.z += v3.z; a3.w += v3.w; }
        }
    }

    a0.x += a1.x; a0.y += a1.y; a0.z += a1.z; a0.w += a1.w;
    a2.x += a3.x; a2.y += a3.y; a2.z += a3.z; a2.w += a3.w;
    a0.x += a2.x; a0.y += a2.y; a0.z += a2.z; a0.w += a2.w;

    // combine the two half-wave partials (lane l <-> lane l^32)
    a0.x += __shfl_xor(a0.x, 32);
    a0.y += __shfl_xor(a0.y, 32);
    a0.z += __shfl_xor(a0.z, 32);
    a0.w += __shfl_xor(a0.w, 32);

    if (half == 0) {
        float inv = (deg > 0) ? (1.f / (float)deg) : 0.f;
        float4 res = make_float4(a0.x * inv, a0.y * inv, a0.z * inv, a0.w * inv);
        ((float4*)out)[(size_t)s * 32 + c4] = res;
    }
}

extern "C" void kernel_launch(void* const* d_in, const int* in_sizes, int n_in,
                              void* d_out, int out_size, void* d_ws, size_t ws_size,
                              hipStream_t stream) {
    const float* input   = (const float*)d_in[0];
    const int*   idxn    = (const int*)d_in[1];
    const int*   seg_ids = (const int*)d_in[2];
    const int*   degs    = (const int*)d_in[3];

    int E = in_sizes[1];
    int S = in_sizes[3];
    float* out = (float*)d_out;

    int nblk = (S + WPB - 1) / WPB;
    seg_mean_wave_kernel<<<nblk, 64 * WPB, 0, stream>>>(
        input, idxn, seg_ids, degs, out, E, S);
}